// Round 6
// baseline (260.254 us; speedup 1.0000x reference)
//
#include <hip/hip_runtime.h>

#define NN 50000
#define NE 600000

typedef unsigned short ushort_t;
typedef ushort_t ushortx8 __attribute__((ext_vector_type(8)));
typedef ushort_t ushortx4 __attribute__((ext_vector_type(4)));
typedef short bf16x8 __attribute__((ext_vector_type(8)));
typedef float f32x4 __attribute__((ext_vector_type(4)));
typedef int intx4 __attribute__((ext_vector_type(4)));
typedef float fltx4 __attribute__((ext_vector_type(4)));

__device__ __forceinline__ float bf2f(ushort_t u) {
    union { unsigned int i; float f; } c;
    c.i = ((unsigned int)u) << 16;
    return c.f;
}
__device__ __forceinline__ ushort_t f2bf(float f) {
    union { float f; unsigned int i; } c;
    c.f = f;
    unsigned int u = c.i;
    unsigned int r = u + 0x7FFFu + ((u >> 16) & 1u);   // RNE
    return (ushort_t)(r >> 16);
}
__device__ __forceinline__ unsigned cvtpk(float lo, float hi) {
    unsigned r;
    asm("v_cvt_pk_bf16_f32 %0, %1, %2" : "=v"(r) : "v"(lo), "v"(hi));
    return r;
}

// ---------------- graph build ----------------

__global__ void k_count(const int* __restrict__ ei, int* __restrict__ cnt) {
    int e = blockIdx.x * 256 + threadIdx.x;
    if (e < NE) {
        int d = __builtin_nontemporal_load(ei + NE + e);
        atomicAdd(&cnt[d], 1);
    }
}

// scan of cnt -> rowptr (exclusive, per-block) + block sums; also dinv
__global__ void k_scan1(const int* __restrict__ cnt, int* __restrict__ rowptr,
                        int* __restrict__ bsum, float* __restrict__ dinv) {
    __shared__ int s[256];
    int t = threadIdx.x;
    int i = blockIdx.x * 256 + t;
    int v = (i < NN) ? cnt[i] : 0;
    if (i < NN) dinv[i] = rsqrtf(1.0f + (float)v);
    s[t] = v;
    __syncthreads();
    for (int d = 1; d < 256; d <<= 1) {
        int tmp = (t >= d) ? s[t - d] : 0;
        __syncthreads();
        s[t] += tmp;
        __syncthreads();
    }
    if (i < NN) rowptr[i] = s[t] - v;
    if (t == 255) bsum[blockIdx.x] = s[255];
}

// blocks 0..255: weight prep (transpose + bf16). block 256: scan of bsum -> boff.
__global__ void k_scan2_prep(int* __restrict__ bsum, int* __restrict__ boff, int nb,
                             const float* __restrict__ Wp1, const float* __restrict__ Wv1,
                             const float* __restrict__ Wp2, const float* __restrict__ Wv2,
                             ushort_t* __restrict__ Wt1, ushort_t* __restrict__ Wt2p,
                             ushort_t* __restrict__ Wt2v) {
    int b = blockIdx.x, t = threadIdx.x;
    if (b < 128) {
        int idx = b * 256 + t;
        int n = idx >> 7, k = idx & 127;
        float v = (n < 128) ? Wp1[k * 128 + n] : Wv1[k * 128 + (n - 128)];
        Wt1[n * 128 + k] = f2bf(v);
    } else if (b < 192) {
        int idx = (b - 128) * 256 + t;
        int n = idx >> 7, k = idx & 127;
        Wt2p[n * 128 + k] = f2bf(Wp2[k * 128 + n]);
    } else if (b < 256) {
        int idx = (b - 192) * 256 + t;
        int n = idx >> 7, k = idx & 127;
        Wt2v[n * 128 + k] = f2bf(Wv2[k * 128 + n]);
    } else {
        __shared__ int s[256];
        int v = (t < nb) ? bsum[t] : 0;
        s[t] = v;
        __syncthreads();
        for (int d = 1; d < 256; d <<= 1) {
            int tmp = (t >= d) ? s[t - d] : 0;
            __syncthreads();
            s[t] += tmp;
            __syncthreads();
        }
        boff[t] = s[t] - v;
    }
}

// rc[i] = {final_start, cnt}
__global__ void k_scan3rc(const int* __restrict__ rowptr, const int* __restrict__ cnt,
                          const int* __restrict__ boff, int2* __restrict__ rc) {
    int i = blockIdx.x * 256 + threadIdx.x;
    if (i < NN) {
        int2 v;
        v.x = rowptr[i] + boff[blockIdx.x];
        v.y = cnt[i];
        rc[i] = v;
    }
}

__global__ void k_fill(const int* __restrict__ ei, const int2* __restrict__ rc,
                       int* __restrict__ fill, const float* __restrict__ dinv,
                       int2* __restrict__ edges) {
    int e = blockIdx.x * 256 + threadIdx.x;
    if (e < NE) {
        int s = __builtin_nontemporal_load(ei + e);
        int d = __builtin_nontemporal_load(ei + NE + e);
        int pos = rc[d].x + atomicAdd(&fill[d], 1);
        int2 pr;
        pr.x = s;
        pr.y = __float_as_int(dinv[s] * dinv[d]);
        edges[pos] = pr;
    }
}

// ---------------- layer-1 MFMA GEMM: C[N,256] = bf16(x[N,128]) @ [Wp1|Wv1] -----------
__global__ __launch_bounds__(256) void k_gemm1(const float* __restrict__ X,
                                               const ushort_t* __restrict__ Wt1,
                                               ushort_t* __restrict__ C, int nrows) {
    __shared__ ushort_t Wl[256 * 128];
    int t = threadIdx.x;
    const ushortx8* Wg = (const ushortx8*)Wt1;
#pragma unroll
    for (int i = 0; i < 16; ++i) {
        int c = i * 256 + t;
        int row = c >> 4, slot = c & 15;
        int db = row * 256 + ((slot * 16) ^ ((row & 7) << 4));
        *(ushortx8*)((char*)Wl + db) = Wg[c];
    }
    __syncthreads();

    int w = t >> 6, l = t & 63, m = l & 15, g = l >> 4;
    int r0 = blockIdx.x * 64 + w * 16;
    if (r0 >= nrows) return;

    const float* Arow = X + (size_t)(r0 + m) * 128;
    bf16x8 af[4];
#pragma unroll
    for (int kk = 0; kk < 4; ++kk) {
        float4 lo = *(const float4*)(Arow + kk * 32 + g * 8);
        float4 hi = *(const float4*)(Arow + kk * 32 + g * 8 + 4);
        union { unsigned u[4]; bf16x8 v; } cv;
        cv.u[0] = cvtpk(lo.x, lo.y);
        cv.u[1] = cvtpk(lo.z, lo.w);
        cv.u[2] = cvtpk(hi.x, hi.y);
        cv.u[3] = cvtpk(hi.z, hi.w);
        af[kk] = cv.v;
    }

    f32x4 acc[16];
#pragma unroll
    for (int nt = 0; nt < 16; ++nt) acc[nt] = (f32x4){0.f, 0.f, 0.f, 0.f};
    int sw = (m & 7) << 4;
#pragma unroll
    for (int nt = 0; nt < 16; ++nt) {
        const char* Wb = (const char*)Wl + (nt * 16 + m) * 256;
#pragma unroll
        for (int kk = 0; kk < 4; ++kk) {
            bf16x8 wf = *(const bf16x8*)(Wb + ((kk * 64 + g * 16) ^ sw));
            acc[nt] = __builtin_amdgcn_mfma_f32_16x16x32_bf16(wf, af[kk], acc[nt], 0, 0, 0);
        }
    }
#pragma unroll
    for (int nt = 0; nt < 16; ++nt) {
        ushortx4 o = {f2bf(acc[nt][0]), f2bf(acc[nt][1]), f2bf(acc[nt][2]), f2bf(acc[nt][3])};
        *(ushortx4*)(C + (size_t)(r0 + m) * 256 + nt * 16 + g * 4) = o;
    }
}

// ---------------- layer-2 dual MFMA GEMM (block-diagonal 256 -> 256) ----------------
__global__ __launch_bounds__(256) void k_gemm2(const ushort_t* __restrict__ A,
                                               const ushort_t* __restrict__ Wp,
                                               const ushort_t* __restrict__ Wv,
                                               ushort_t* __restrict__ C, int nrows) {
    __shared__ ushort_t Wl[2 * 128 * 128];
    int t = threadIdx.x;
    const ushortx8* Wgp = (const ushortx8*)Wp;
    const ushortx8* Wgv = (const ushortx8*)Wv;
#pragma unroll
    for (int i = 0; i < 8; ++i) {
        int c = i * 256 + t;
        int row = c >> 4, slot = c & 15;
        int db = row * 256 + ((slot * 16) ^ ((row & 7) << 4));
        *(ushortx8*)((char*)Wl + db) = Wgp[c];
        *(ushortx8*)((char*)Wl + 32768 + db) = Wgv[c];
    }
    __syncthreads();

    int w = t >> 6, l = t & 63, m = l & 15, g = l >> 4;
    int r0 = blockIdx.x * 64 + w * 16;
    if (r0 >= nrows) return;

    const ushort_t* Arow = A + (size_t)(r0 + m) * 256;
    bf16x8 alo[4], ahi[4];
#pragma unroll
    for (int kk = 0; kk < 4; ++kk) {
        alo[kk] = *(const bf16x8*)(Arow + kk * 32 + g * 8);
        ahi[kk] = *(const bf16x8*)(Arow + 128 + kk * 32 + g * 8);
    }

    f32x4 accp[8], accv[8];
#pragma unroll
    for (int nt = 0; nt < 8; ++nt) {
        accp[nt] = (f32x4){0.f, 0.f, 0.f, 0.f};
        accv[nt] = (f32x4){0.f, 0.f, 0.f, 0.f};
    }
    int sw = (m & 7) << 4;
#pragma unroll
    for (int nt = 0; nt < 8; ++nt) {
        const char* Wbp = (const char*)Wl + (nt * 16 + m) * 256;
        const char* Wbv = Wbp + 32768;
#pragma unroll
        for (int kk = 0; kk < 4; ++kk) {
            int off = (kk * 64 + g * 16) ^ sw;
            bf16x8 wfp = *(const bf16x8*)(Wbp + off);
            accp[nt] = __builtin_amdgcn_mfma_f32_16x16x32_bf16(wfp, alo[kk], accp[nt], 0, 0, 0);
            bf16x8 wfv = *(const bf16x8*)(Wbv + off);
            accv[nt] = __builtin_amdgcn_mfma_f32_16x16x32_bf16(wfv, ahi[kk], accv[nt], 0, 0, 0);
        }
    }
#pragma unroll
    for (int nt = 0; nt < 8; ++nt) {
        ushortx4 op = {f2bf(accp[nt][0]), f2bf(accp[nt][1]), f2bf(accp[nt][2]), f2bf(accp[nt][3])};
        ushortx4 ov = {f2bf(accv[nt][0]), f2bf(accv[nt][1]), f2bf(accv[nt][2]), f2bf(accv[nt][3])};
        *(ushortx4*)(C + (size_t)(r0 + m) * 256 + nt * 16 + g * 4) = op;
        *(ushortx4*)(C + (size_t)(r0 + m) * 256 + 128 + nt * 16 + g * 4) = ov;
    }
}

// ---------------- fused aggregation, 256 features, bf16 in/out ----------------
// wave per node; 2 teams of 32 lanes (16B each); predicated 8-slot gather burst.
__global__ __launch_bounds__(256) void k_agg256(const ushort_t* __restrict__ H,
                                                ushort_t* __restrict__ OUT,
                                                const float* __restrict__ b_lo,
                                                const float* __restrict__ b_hi,
                                                const float* __restrict__ dinv,
                                                const int2* __restrict__ rc,
                                                const int2* __restrict__ edges) {
    int wv = threadIdx.x >> 6;
    int l = threadIdx.x & 63;
    int i = blockIdx.x * 4 + wv;
    if (i >= NN) return;
    int h = l >> 5, q = l & 31;
    const ushortx8* H8 = (const ushortx8*)H;

    float a0[8] = {}, a1[8] = {};
    float di = dinv[i];
    if (h == 0) {
        float ws = di * di;
        ushortx8 hv = H8[(size_t)i * 32 + q];
#pragma unroll
        for (int k = 0; k < 8; ++k) a0[k] = ws * bf2f(hv[k]);
    }
    int2 rcv = rc[i];
    int st = rcv.x, n = rcv.y;

    for (int j = h; j < n; j += 16) {
        int jb = st + (j - h);          // even pair base
        float w[8];
        int idx[8];
#pragma unroll
        for (int s = 0; s < 8; ++s) {
            int jj = j + 2 * s;         // this team's edge index within row
            int ea = jb + 2 * s;        // pair base
            ea = (ea > NE - 2) ? (NE - 2) : ea;
            intx4 em = __builtin_nontemporal_load((const intx4*)(edges + ea));
            idx[s] = h ? em.z : em.x;
            int wz = h ? em.w : em.y;
            w[s] = (jj < n) ? __int_as_float(wz) : 0.f;
        }
        ushortx8 hh[8];
#pragma unroll
        for (int s = 0; s < 8; ++s) hh[s] = H8[(size_t)idx[s] * 32 + q];
#pragma unroll
        for (int s = 0; s < 8; ++s) {
            float* a = (s & 1) ? a1 : a0;
#pragma unroll
            for (int k = 0; k < 8; ++k) a[k] += w[s] * bf2f(hh[s][k]);
        }
    }
#pragma unroll
    for (int k = 0; k < 8; ++k) a0[k] += a1[k];
#pragma unroll
    for (int k = 0; k < 8; ++k) a0[k] += __shfl_xor(a0[k], 32, 64);

    if (h == 0) {
        const float* bb = (q < 16) ? (b_lo + q * 8) : (b_hi + (q - 16) * 8);
        float4 b0 = *(const float4*)bb;
        float4 b1 = *(const float4*)(bb + 4);
        float r[8];
        r[0] = fmaxf(a0[0] + b0.x, 0.f); r[1] = fmaxf(a0[1] + b0.y, 0.f);
        r[2] = fmaxf(a0[2] + b0.z, 0.f); r[3] = fmaxf(a0[3] + b0.w, 0.f);
        r[4] = fmaxf(a0[4] + b1.x, 0.f); r[5] = fmaxf(a0[5] + b1.y, 0.f);
        r[6] = fmaxf(a0[6] + b1.z, 0.f); r[7] = fmaxf(a0[7] + b1.w, 0.f);
        ushortx8 o = {f2bf(r[0]), f2bf(r[1]), f2bf(r[2]), f2bf(r[3]),
                      f2bf(r[4]), f2bf(r[5]), f2bf(r[6]), f2bf(r[7])};
        __builtin_nontemporal_store(o, (ushortx8*)OUT + (size_t)i * 32 + q);
    }
}

// ---------------- small GEMM (bf16 in): fs[:,0:8]=f2[:,0:128]@Wp3 ; fs[:,8]=f2[:,128:256]@Wv3
__global__ __launch_bounds__(256) void k_small(const ushort_t* __restrict__ F2,
                                               const float* __restrict__ Wp3,
                                               const float* __restrict__ Wv3,
                                               float* __restrict__ FS) {
    __shared__ float Wp[8 * 128];
    __shared__ float Wv[128];
    int t = threadIdx.x;
    for (int j = t; j < 1024; j += 256) {
        int k = j >> 3, c = j & 7;
        Wp[c * 128 + k] = Wp3[j];
    }
    if (t < 128) Wv[t] = Wv3[t];
    __syncthreads();
    int row = blockIdx.x * 256 + t;
    if (row >= NN) return;
    const ushortx8* F8 = (const ushortx8*)F2;
    size_t base = (size_t)row * 32;
    float acc[9] = {};
#pragma unroll 2
    for (int kc = 0; kc < 16; ++kc) {
        ushortx8 p = F8[base + kc];
        ushortx8 v = F8[base + 16 + kc];
#pragma unroll
        for (int jj = 0; jj < 8; ++jj) {
            float pv = bf2f(p[jj]);
            int k = kc * 8 + jj;
#pragma unroll
            for (int c = 0; c < 8; ++c) acc[c] += pv * Wp[c * 128 + k];
            acc[8] += bf2f(v[jj]) * Wv[k];
        }
    }
    float4* FSo = (float4*)(FS + (size_t)row * 12);
    float4 o0 = {acc[0], acc[1], acc[2], acc[3]};
    float4 o1 = {acc[4], acc[5], acc[6], acc[7]};
    float4 o2 = {acc[8], 0.f, 0.f, 0.f};
    FSo[0] = o0; FSo[1] = o1; FSo[2] = o2;
}

// ---------------- final fused aggregation (8 logits + 1 value) ----------------
__global__ void k_agg9(const float* __restrict__ FS, float* __restrict__ out_logits,
                       float* __restrict__ out_v, const float* __restrict__ bp3,
                       const float* __restrict__ bv3, const float* __restrict__ dinv,
                       const int2* __restrict__ rc, const int2* __restrict__ edges) {
    int i = blockIdx.x * 256 + threadIdx.x;
    if (i >= NN) return;
    float di = dinv[i];
    float w0 = di * di;
    const float4* F = (const float4*)FS;
    size_t b0 = (size_t)i * 3;
    float4 x0 = F[b0], x1 = F[b0 + 1], x2 = F[b0 + 2];
    float a[9];
    a[0] = w0 * x0.x; a[1] = w0 * x0.y; a[2] = w0 * x0.z; a[3] = w0 * x0.w;
    a[4] = w0 * x1.x; a[5] = w0 * x1.y; a[6] = w0 * x1.z; a[7] = w0 * x1.w;
    a[8] = w0 * x2.x;
    int2 rcv = rc[i];
    int st = rcv.x, n = rcv.y;
    for (int j = 0; j < n; ++j) {
        int2 e = edges[st + j];
        float w = __int_as_float(e.y);
        size_t sb = (size_t)e.x * 3;
        float4 y0 = F[sb], y1 = F[sb + 1], y2 = F[sb + 2];
        a[0] += w * y0.x; a[1] += w * y0.y; a[2] += w * y0.z; a[3] += w * y0.w;
        a[4] += w * y1.x; a[5] += w * y1.y; a[6] += w * y1.z; a[7] += w * y1.w;
        a[8] += w * y2.x;
    }
    float4 bpa = *(const float4*)bp3;
    float4 bpb = *(const float4*)(bp3 + 4);
    fltx4 o0 = {a[0] + bpa.x, a[1] + bpa.y, a[2] + bpa.z, a[3] + bpa.w};
    fltx4 o1 = {a[4] + bpb.x, a[5] + bpb.y, a[6] + bpb.z, a[7] + bpb.w};
    __builtin_nontemporal_store(o0, (fltx4*)out_logits + (size_t)i * 2);
    __builtin_nontemporal_store(o1, (fltx4*)out_logits + (size_t)i * 2 + 1);
    __builtin_nontemporal_store(a[8] + bv3[0], out_v + i);
}

// ---------------- launcher ----------------
extern "C" void kernel_launch(void* const* d_in, const int* in_sizes, int n_in,
                              void* d_out, int out_size, void* d_ws, size_t ws_size,
                              hipStream_t stream) {
    const float* x   = (const float*)d_in[0];
    const int*   ei  = (const int*)d_in[1];
    const float* Wp1 = (const float*)d_in[2],  *bp1 = (const float*)d_in[3];
    const float* Wp2 = (const float*)d_in[4],  *bp2 = (const float*)d_in[5];
    const float* Wp3 = (const float*)d_in[6],  *bp3 = (const float*)d_in[7];
    const float* Wv1 = (const float*)d_in[8],  *bv1 = (const float*)d_in[9];
    const float* Wv2 = (const float*)d_in[10], *bv2 = (const float*)d_in[11];
    const float* Wv3 = (const float*)d_in[12], *bv3 = (const float*)d_in[13];
    float* out_logits = (float*)d_out;
    float* out_v = (float*)d_out + (size_t)NN * 8;

    char* w = (char*)d_ws;
    auto alloc = [&](size_t bytes) {
        char* p = w;
        w += (bytes + 255) & ~(size_t)255;
        return p;
    };
    int*      cntfill = (int*)alloc((size_t)2 * NN * 4);
    int*      cnt    = cntfill;
    int*      fill   = cntfill + NN;
    int*      rowptr = (int*)alloc(NN * 4);
    int*      bsum   = (int*)alloc(256 * 4);
    int*      boff   = (int*)alloc(256 * 4);
    float*    dinv   = (float*)alloc(NN * 4);
    int2*     rc     = (int2*)alloc((size_t)NN * 8);
    int2*     edges  = (int2*)alloc((size_t)NE * 8);
    ushort_t* Wt1    = (ushort_t*)alloc(256 * 128 * 2);
    ushort_t* Wt2p   = (ushort_t*)alloc(128 * 128 * 2);
    ushort_t* Wt2v   = (ushort_t*)alloc(128 * 128 * 2);
    ushort_t* Hb     = (ushort_t*)alloc((size_t)NN * 256 * 2);
    ushort_t* f1b    = (ushort_t*)alloc((size_t)NN * 256 * 2);
    ushort_t* f2b    = (ushort_t*)alloc((size_t)NN * 256 * 2);
    float*    fs     = (float*)alloc((size_t)NN * 12 * 4);

    const int NB = (NN + 255) / 256;   // 196
    const int EB = (NE + 255) / 256;
    const int GB = (NN + 63) / 64;     // 782
    const int AB = NN / 4;             // 12500

    (void)hipMemsetAsync(cntfill, 0, (size_t)2 * NN * 4, stream);
    k_count<<<EB, 256, 0, stream>>>(ei, cnt);
    k_scan1<<<NB, 256, 0, stream>>>(cnt, rowptr, bsum, dinv);
    k_scan2_prep<<<257, 256, 0, stream>>>(bsum, boff, NB, Wp1, Wv1, Wp2, Wv2,
                                          Wt1, Wt2p, Wt2v);
    k_scan3rc<<<NB, 256, 0, stream>>>(rowptr, cnt, boff, rc);
    k_fill<<<EB, 256, 0, stream>>>(ei, rc, fill, dinv, edges);

    // layer 1 (policy | value fused into 256 cols)
    k_gemm1<<<GB, 256, 0, stream>>>(x, Wt1, Hb, NN);
    k_agg256<<<AB, 256, 0, stream>>>(Hb, f1b, bp1, bv1, dinv, rc, edges);
    // layer 2 (block-diagonal, fused)
    k_gemm2<<<GB, 256, 0, stream>>>(f1b, Wt2p, Wt2v, Hb, NN);
    k_agg256<<<AB, 256, 0, stream>>>(Hb, f2b, bp2, bv2, dinv, rc, edges);
    // layer 3 (fp32 accumulate from bf16 input)
    k_small<<<NB, 256, 0, stream>>>(f2b, Wp3, Wv3, fs);
    k_agg9<<<NB, 256, 0, stream>>>(fs, out_logits, out_v, bp3, bv3, dinv, rc, edges);
}

// Round 7
// 237.627 us; speedup vs baseline: 1.0952x; 1.0952x over previous
//
#include <hip/hip_runtime.h>

#define NN 50000
#define NE 600000

typedef unsigned short ushort_t;
typedef ushort_t ushortx8 __attribute__((ext_vector_type(8)));
typedef ushort_t ushortx4 __attribute__((ext_vector_type(4)));
typedef short bf16x8 __attribute__((ext_vector_type(8)));
typedef float f32x4 __attribute__((ext_vector_type(4)));
typedef int intx2 __attribute__((ext_vector_type(2)));
typedef float fltx4 __attribute__((ext_vector_type(4)));

__device__ __forceinline__ float bf2f(ushort_t u) {
    union { unsigned int i; float f; } c;
    c.i = ((unsigned int)u) << 16;
    return c.f;
}
__device__ __forceinline__ ushort_t f2bf(float f) {
    union { float f; unsigned int i; } c;
    c.f = f;
    unsigned int u = c.i;
    unsigned int r = u + 0x7FFFu + ((u >> 16) & 1u);   // RNE
    return (ushort_t)(r >> 16);
}
__device__ __forceinline__ unsigned cvtpk(float lo, float hi) {
    unsigned r;
    asm("v_cvt_pk_bf16_f32 %0, %1, %2" : "=v"(r) : "v"(lo), "v"(hi));
    return r;
}

// ---------------- graph build ----------------

__global__ void k_count(const int* __restrict__ ei, int* __restrict__ cnt) {
    int e = blockIdx.x * 256 + threadIdx.x;
    if (e < NE) {
        int d = __builtin_nontemporal_load(ei + NE + e);
        atomicAdd(&cnt[d], 1);
    }
}

// scan of cnt -> rowptr (exclusive, per-block) + block sums; also dinv
__global__ void k_scan1(const int* __restrict__ cnt, int* __restrict__ rowptr,
                        int* __restrict__ bsum, float* __restrict__ dinv) {
    __shared__ int s[256];
    int t = threadIdx.x;
    int i = blockIdx.x * 256 + t;
    int v = (i < NN) ? cnt[i] : 0;
    if (i < NN) dinv[i] = rsqrtf(1.0f + (float)v);
    s[t] = v;
    __syncthreads();
    for (int d = 1; d < 256; d <<= 1) {
        int tmp = (t >= d) ? s[t - d] : 0;
        __syncthreads();
        s[t] += tmp;
        __syncthreads();
    }
    if (i < NN) rowptr[i] = s[t] - v;
    if (t == 255) bsum[blockIdx.x] = s[255];
}

// blocks 0..255: weight prep (transpose + bf16). block 256: scan of bsum -> boff.
__global__ void k_scan2_prep(int* __restrict__ bsum, int* __restrict__ boff, int nb,
                             const float* __restrict__ Wp1, const float* __restrict__ Wv1,
                             const float* __restrict__ Wp2, const float* __restrict__ Wv2,
                             ushort_t* __restrict__ Wt1, ushort_t* __restrict__ Wt2p,
                             ushort_t* __restrict__ Wt2v) {
    int b = blockIdx.x, t = threadIdx.x;
    if (b < 128) {
        int idx = b * 256 + t;
        int n = idx >> 7, k = idx & 127;
        float v = (n < 128) ? Wp1[k * 128 + n] : Wv1[k * 128 + (n - 128)];
        Wt1[n * 128 + k] = f2bf(v);
    } else if (b < 192) {
        int idx = (b - 128) * 256 + t;
        int n = idx >> 7, k = idx & 127;
        Wt2p[n * 128 + k] = f2bf(Wp2[k * 128 + n]);
    } else if (b < 256) {
        int idx = (b - 192) * 256 + t;
        int n = idx >> 7, k = idx & 127;
        Wt2v[n * 128 + k] = f2bf(Wv2[k * 128 + n]);
    } else {
        __shared__ int s[256];
        int v = (t < nb) ? bsum[t] : 0;
        s[t] = v;
        __syncthreads();
        for (int d = 1; d < 256; d <<= 1) {
            int tmp = (t >= d) ? s[t - d] : 0;
            __syncthreads();
            s[t] += tmp;
            __syncthreads();
        }
        boff[t] = s[t] - v;
    }
}

// rc[i] = {final_start, cnt}
__global__ void k_scan3rc(const int* __restrict__ rowptr, const int* __restrict__ cnt,
                          const int* __restrict__ boff, int2* __restrict__ rc) {
    int i = blockIdx.x * 256 + threadIdx.x;
    if (i < NN) {
        int2 v;
        v.x = rowptr[i] + boff[blockIdx.x];
        v.y = cnt[i];
        rc[i] = v;
    }
}

__global__ void k_fill(const int* __restrict__ ei, const int2* __restrict__ rc,
                       int* __restrict__ fill, const float* __restrict__ dinv,
                       int2* __restrict__ edges) {
    int e = blockIdx.x * 256 + threadIdx.x;
    if (e < NE) {
        int s = __builtin_nontemporal_load(ei + e);
        int d = __builtin_nontemporal_load(ei + NE + e);
        int pos = rc[d].x + atomicAdd(&fill[d], 1);
        int2 pr;
        pr.x = s;
        pr.y = __float_as_int(dinv[s] * dinv[d]);
        edges[pos] = pr;
    }
}

// ---------------- layer-1 MFMA GEMM: C[N,256] = bf16(x[N,128]) @ [Wp1|Wv1] -----------
__global__ __launch_bounds__(256) void k_gemm1(const float* __restrict__ X,
                                               const ushort_t* __restrict__ Wt1,
                                               ushort_t* __restrict__ C, int nrows) {
    __shared__ ushort_t Wl[256 * 128];
    int t = threadIdx.x;
    const ushortx8* Wg = (const ushortx8*)Wt1;
#pragma unroll
    for (int i = 0; i < 16; ++i) {
        int c = i * 256 + t;
        int row = c >> 4, slot = c & 15;
        int db = row * 256 + ((slot * 16) ^ ((row & 7) << 4));
        *(ushortx8*)((char*)Wl + db) = Wg[c];
    }
    __syncthreads();

    int w = t >> 6, l = t & 63, m = l & 15, g = l >> 4;
    int r0 = blockIdx.x * 64 + w * 16;
    if (r0 >= nrows) return;

    const float* Arow = X + (size_t)(r0 + m) * 128;
    bf16x8 af[4];
#pragma unroll
    for (int kk = 0; kk < 4; ++kk) {
        float4 lo = *(const float4*)(Arow + kk * 32 + g * 8);
        float4 hi = *(const float4*)(Arow + kk * 32 + g * 8 + 4);
        union { unsigned u[4]; bf16x8 v; } cv;
        cv.u[0] = cvtpk(lo.x, lo.y);
        cv.u[1] = cvtpk(lo.z, lo.w);
        cv.u[2] = cvtpk(hi.x, hi.y);
        cv.u[3] = cvtpk(hi.z, hi.w);
        af[kk] = cv.v;
    }

    f32x4 acc[16];
#pragma unroll
    for (int nt = 0; nt < 16; ++nt) acc[nt] = (f32x4){0.f, 0.f, 0.f, 0.f};
    int sw = (m & 7) << 4;
#pragma unroll
    for (int nt = 0; nt < 16; ++nt) {
        const char* Wb = (const char*)Wl + (nt * 16 + m) * 256;
#pragma unroll
        for (int kk = 0; kk < 4; ++kk) {
            bf16x8 wf = *(const bf16x8*)(Wb + ((kk * 64 + g * 16) ^ sw));
            acc[nt] = __builtin_amdgcn_mfma_f32_16x16x32_bf16(wf, af[kk], acc[nt], 0, 0, 0);
        }
    }
#pragma unroll
    for (int nt = 0; nt < 16; ++nt) {
        ushortx4 o = {f2bf(acc[nt][0]), f2bf(acc[nt][1]), f2bf(acc[nt][2]), f2bf(acc[nt][3])};
        *(ushortx4*)(C + (size_t)(r0 + m) * 256 + nt * 16 + g * 4) = o;
    }
}

// ---------------- layer-2 dual MFMA GEMM (block-diagonal 256 -> 256) ----------------
__global__ __launch_bounds__(256) void k_gemm2(const ushort_t* __restrict__ A,
                                               const ushort_t* __restrict__ Wp,
                                               const ushort_t* __restrict__ Wv,
                                               ushort_t* __restrict__ C, int nrows) {
    __shared__ ushort_t Wl[2 * 128 * 128];
    int t = threadIdx.x;
    const ushortx8* Wgp = (const ushortx8*)Wp;
    const ushortx8* Wgv = (const ushortx8*)Wv;
#pragma unroll
    for (int i = 0; i < 8; ++i) {
        int c = i * 256 + t;
        int row = c >> 4, slot = c & 15;
        int db = row * 256 + ((slot * 16) ^ ((row & 7) << 4));
        *(ushortx8*)((char*)Wl + db) = Wgp[c];
        *(ushortx8*)((char*)Wl + 32768 + db) = Wgv[c];
    }
    __syncthreads();

    int w = t >> 6, l = t & 63, m = l & 15, g = l >> 4;
    int r0 = blockIdx.x * 64 + w * 16;
    if (r0 >= nrows) return;

    const ushort_t* Arow = A + (size_t)(r0 + m) * 256;
    bf16x8 alo[4], ahi[4];
#pragma unroll
    for (int kk = 0; kk < 4; ++kk) {
        alo[kk] = *(const bf16x8*)(Arow + kk * 32 + g * 8);
        ahi[kk] = *(const bf16x8*)(Arow + 128 + kk * 32 + g * 8);
    }

    f32x4 accp[8], accv[8];
#pragma unroll
    for (int nt = 0; nt < 8; ++nt) {
        accp[nt] = (f32x4){0.f, 0.f, 0.f, 0.f};
        accv[nt] = (f32x4){0.f, 0.f, 0.f, 0.f};
    }
    int sw = (m & 7) << 4;
#pragma unroll
    for (int nt = 0; nt < 8; ++nt) {
        const char* Wbp = (const char*)Wl + (nt * 16 + m) * 256;
        const char* Wbv = Wbp + 32768;
#pragma unroll
        for (int kk = 0; kk < 4; ++kk) {
            int off = (kk * 64 + g * 16) ^ sw;
            bf16x8 wfp = *(const bf16x8*)(Wbp + off);
            accp[nt] = __builtin_amdgcn_mfma_f32_16x16x32_bf16(wfp, alo[kk], accp[nt], 0, 0, 0);
            bf16x8 wfv = *(const bf16x8*)(Wbv + off);
            accv[nt] = __builtin_amdgcn_mfma_f32_16x16x32_bf16(wfv, ahi[kk], accv[nt], 0, 0, 0);
        }
    }
#pragma unroll
    for (int nt = 0; nt < 8; ++nt) {
        ushortx4 op = {f2bf(accp[nt][0]), f2bf(accp[nt][1]), f2bf(accp[nt][2]), f2bf(accp[nt][3])};
        ushortx4 ov = {f2bf(accv[nt][0]), f2bf(accv[nt][1]), f2bf(accv[nt][2]), f2bf(accv[nt][3])};
        *(ushortx4*)(C + (size_t)(r0 + m) * 256 + nt * 16 + g * 4) = op;
        *(ushortx4*)(C + (size_t)(r0 + m) * 256 + 128 + nt * 16 + g * 4) = ov;
    }
}

// ---------------- fused aggregation, 256 features, bf16 in/out ----------------
// wave per node; 2 teams of 32 lanes (16B each). Predicated 4-slot burst:
// dead slots gather row i (L1-hot after self-load) with weight 0 -> no wasted HBM.
__global__ __launch_bounds__(256) void k_agg256(const ushort_t* __restrict__ H,
                                                ushort_t* __restrict__ OUT,
                                                const float* __restrict__ b_lo,
                                                const float* __restrict__ b_hi,
                                                const float* __restrict__ dinv,
                                                const int2* __restrict__ rc,
                                                const int2* __restrict__ edges) {
    int wv = threadIdx.x >> 6;
    int l = threadIdx.x & 63;
    int i = blockIdx.x * 4 + wv;
    if (i >= NN) return;
    int h = l >> 5, q = l & 31;
    const ushortx8* H8 = (const ushortx8*)H;

    float a0[8] = {}, a1[8] = {};
    // both teams load the self row (puts it in L1 for dead-slot gathers);
    // team 1 scales by 0 so it contributes exactly once.
    float di = dinv[i];
    float ws = (h == 0) ? di * di : 0.f;
    ushortx8 hv = H8[(size_t)i * 32 + q];
#pragma unroll
    for (int k = 0; k < 8; ++k) a0[k] = ws * bf2f(hv[k]);

    int2 rcv = rc[i];
    int st = rcv.x, n = rcv.y;

    for (int j = h; j < n; j += 8) {
        int idx[4];
        float w[4];
#pragma unroll
        for (int s = 0; s < 4; ++s) {
            int jj = j + 2 * s;            // this team's edge index within row
            bool valid = jj < n;
            intx2 em = __builtin_nontemporal_load(
                (const intx2*)edges + (valid ? st + jj : st));
            idx[s] = valid ? em.x : i;
            w[s] = valid ? __int_as_float(em.y) : 0.f;
        }
        ushortx8 hh[4];
#pragma unroll
        for (int s = 0; s < 4; ++s) hh[s] = H8[(size_t)idx[s] * 32 + q];
#pragma unroll
        for (int k = 0; k < 8; ++k) a0[k] += w[0] * bf2f(hh[0][k]);
#pragma unroll
        for (int k = 0; k < 8; ++k) a1[k] += w[1] * bf2f(hh[1][k]);
#pragma unroll
        for (int k = 0; k < 8; ++k) a0[k] += w[2] * bf2f(hh[2][k]);
#pragma unroll
        for (int k = 0; k < 8; ++k) a1[k] += w[3] * bf2f(hh[3][k]);
    }
#pragma unroll
    for (int k = 0; k < 8; ++k) a0[k] += a1[k];
#pragma unroll
    for (int k = 0; k < 8; ++k) a0[k] += __shfl_xor(a0[k], 32, 64);

    if (h == 0) {
        const float* bb = (q < 16) ? (b_lo + q * 8) : (b_hi + (q - 16) * 8);
        float4 b0 = *(const float4*)bb;
        float4 b1 = *(const float4*)(bb + 4);
        float r[8];
        r[0] = fmaxf(a0[0] + b0.x, 0.f); r[1] = fmaxf(a0[1] + b0.y, 0.f);
        r[2] = fmaxf(a0[2] + b0.z, 0.f); r[3] = fmaxf(a0[3] + b0.w, 0.f);
        r[4] = fmaxf(a0[4] + b1.x, 0.f); r[5] = fmaxf(a0[5] + b1.y, 0.f);
        r[6] = fmaxf(a0[6] + b1.z, 0.f); r[7] = fmaxf(a0[7] + b1.w, 0.f);
        ushortx8 o = {f2bf(r[0]), f2bf(r[1]), f2bf(r[2]), f2bf(r[3]),
                      f2bf(r[4]), f2bf(r[5]), f2bf(r[6]), f2bf(r[7])};
        __builtin_nontemporal_store(o, (ushortx8*)OUT + (size_t)i * 32 + q);
    }
}

// ---------------- small GEMM (bf16 in): fs[:,0:8]=f2[:,0:128]@Wp3 ; fs[:,8]=f2[:,128:256]@Wv3
__global__ __launch_bounds__(256) void k_small(const ushort_t* __restrict__ F2,
                                               const float* __restrict__ Wp3,
                                               const float* __restrict__ Wv3,
                                               float* __restrict__ FS) {
    __shared__ float Wp[8 * 128];
    __shared__ float Wv[128];
    int t = threadIdx.x;
    for (int j = t; j < 1024; j += 256) {
        int k = j >> 3, c = j & 7;
        Wp[c * 128 + k] = Wp3[j];
    }
    if (t < 128) Wv[t] = Wv3[t];
    __syncthreads();
    int row = blockIdx.x * 256 + t;
    if (row >= NN) return;
    const ushortx8* F8 = (const ushortx8*)F2;
    size_t base = (size_t)row * 32;
    float acc[9] = {};
#pragma unroll 2
    for (int kc = 0; kc < 16; ++kc) {
        ushortx8 p = F8[base + kc];
        ushortx8 v = F8[base + 16 + kc];
#pragma unroll
        for (int jj = 0; jj < 8; ++jj) {
            float pv = bf2f(p[jj]);
            int k = kc * 8 + jj;
#pragma unroll
            for (int c = 0; c < 8; ++c) acc[c] += pv * Wp[c * 128 + k];
            acc[8] += bf2f(v[jj]) * Wv[k];
        }
    }
    float4* FSo = (float4*)(FS + (size_t)row * 12);
    float4 o0 = {acc[0], acc[1], acc[2], acc[3]};
    float4 o1 = {acc[4], acc[5], acc[6], acc[7]};
    float4 o2 = {acc[8], 0.f, 0.f, 0.f};
    FSo[0] = o0; FSo[1] = o1; FSo[2] = o2;
}

// ---------------- final fused aggregation (8 logits + 1 value) ----------------
__global__ void k_agg9(const float* __restrict__ FS, float* __restrict__ out_logits,
                       float* __restrict__ out_v, const float* __restrict__ bp3,
                       const float* __restrict__ bv3, const float* __restrict__ dinv,
                       const int2* __restrict__ rc, const int2* __restrict__ edges) {
    int i = blockIdx.x * 256 + threadIdx.x;
    if (i >= NN) return;
    float di = dinv[i];
    float w0 = di * di;
    const float4* F = (const float4*)FS;
    size_t b0 = (size_t)i * 3;
    float4 x0 = F[b0], x1 = F[b0 + 1], x2 = F[b0 + 2];
    float a[9];
    a[0] = w0 * x0.x; a[1] = w0 * x0.y; a[2] = w0 * x0.z; a[3] = w0 * x0.w;
    a[4] = w0 * x1.x; a[5] = w0 * x1.y; a[6] = w0 * x1.z; a[7] = w0 * x1.w;
    a[8] = w0 * x2.x;
    int2 rcv = rc[i];
    int st = rcv.x, n = rcv.y;
    for (int j = 0; j < n; ++j) {
        int2 e = edges[st + j];
        float w = __int_as_float(e.y);
        size_t sb = (size_t)e.x * 3;
        float4 y0 = F[sb], y1 = F[sb + 1], y2 = F[sb + 2];
        a[0] += w * y0.x; a[1] += w * y0.y; a[2] += w * y0.z; a[3] += w * y0.w;
        a[4] += w * y1.x; a[5] += w * y1.y; a[6] += w * y1.z; a[7] += w * y1.w;
        a[8] += w * y2.x;
    }
    float4 bpa = *(const float4*)bp3;
    float4 bpb = *(const float4*)(bp3 + 4);
    fltx4 o0 = {a[0] + bpa.x, a[1] + bpa.y, a[2] + bpa.z, a[3] + bpa.w};
    fltx4 o1 = {a[4] + bpb.x, a[5] + bpb.y, a[6] + bpb.z, a[7] + bpb.w};
    __builtin_nontemporal_store(o0, (fltx4*)out_logits + (size_t)i * 2);
    __builtin_nontemporal_store(o1, (fltx4*)out_logits + (size_t)i * 2 + 1);
    __builtin_nontemporal_store(a[8] + bv3[0], out_v + i);
}

// ---------------- launcher ----------------
extern "C" void kernel_launch(void* const* d_in, const int* in_sizes, int n_in,
                              void* d_out, int out_size, void* d_ws, size_t ws_size,
                              hipStream_t stream) {
    const float* x   = (const float*)d_in[0];
    const int*   ei  = (const int*)d_in[1];
    const float* Wp1 = (const float*)d_in[2],  *bp1 = (const float*)d_in[3];
    const float* Wp2 = (const float*)d_in[4],  *bp2 = (const float*)d_in[5];
    const float* Wp3 = (const float*)d_in[6],  *bp3 = (const float*)d_in[7];
    const float* Wv1 = (const float*)d_in[8],  *bv1 = (const float*)d_in[9];
    const float* Wv2 = (const float*)d_in[10], *bv2 = (const float*)d_in[11];
    const float* Wv3 = (const float*)d_in[12], *bv3 = (const float*)d_in[13];
    float* out_logits = (float*)d_out;
    float* out_v = (float*)d_out + (size_t)NN * 8;

    char* w = (char*)d_ws;
    auto alloc = [&](size_t bytes) {
        char* p = w;
        w += (bytes + 255) & ~(size_t)255;
        return p;
    };
    int*      cntfill = (int*)alloc((size_t)2 * NN * 4);
    int*      cnt    = cntfill;
    int*      fill   = cntfill + NN;
    int*      rowptr = (int*)alloc(NN * 4);
    int*      bsum   = (int*)alloc(256 * 4);
    int*      boff   = (int*)alloc(256 * 4);
    float*    dinv   = (float*)alloc(NN * 4);
    int2*     rc     = (int2*)alloc((size_t)NN * 8);
    int2*     edges  = (int2*)alloc((size_t)NE * 8);
    ushort_t* Wt1    = (ushort_t*)alloc(256 * 128 * 2);
    ushort_t* Wt2p   = (ushort_t*)alloc(128 * 128 * 2);
    ushort_t* Wt2v   = (ushort_t*)alloc(128 * 128 * 2);
    ushort_t* Hb     = (ushort_t*)alloc((size_t)NN * 256 * 2);
    ushort_t* f1b    = (ushort_t*)alloc((size_t)NN * 256 * 2);
    ushort_t* f2b    = (ushort_t*)alloc((size_t)NN * 256 * 2);
    float*    fs     = (float*)alloc((size_t)NN * 12 * 4);

    const int NB = (NN + 255) / 256;   // 196
    const int EB = (NE + 255) / 256;
    const int GB = (NN + 63) / 64;     // 782
    const int AB = NN / 4;             // 12500

    (void)hipMemsetAsync(cntfill, 0, (size_t)2 * NN * 4, stream);
    k_count<<<EB, 256, 0, stream>>>(ei, cnt);
    k_scan1<<<NB, 256, 0, stream>>>(cnt, rowptr, bsum, dinv);
    k_scan2_prep<<<257, 256, 0, stream>>>(bsum, boff, NB, Wp1, Wv1, Wp2, Wv2,
                                          Wt1, Wt2p, Wt2v);
    k_scan3rc<<<NB, 256, 0, stream>>>(rowptr, cnt, boff, rc);
    k_fill<<<EB, 256, 0, stream>>>(ei, rc, fill, dinv, edges);

    // layer 1 (policy | value fused into 256 cols)
    k_gemm1<<<GB, 256, 0, stream>>>(x, Wt1, Hb, NN);
    k_agg256<<<AB, 256, 0, stream>>>(Hb, f1b, bp1, bv1, dinv, rc, edges);
    // layer 2 (block-diagonal, fused)
    k_gemm2<<<GB, 256, 0, stream>>>(f1b, Wt2p, Wt2v, Hb, NN);
    k_agg256<<<AB, 256, 0, stream>>>(Hb, f2b, bp2, bv2, dinv, rc, edges);
    // layer 3 (fp32 accumulate from bf16 input)
    k_small<<<NB, 256, 0, stream>>>(f2b, Wp3, Wv3, fs);
    k_agg9<<<NB, 256, 0, stream>>>(fs, out_logits, out_v, bp3, bv3, dinv, rc, edges);
}

// Round 8
// 219.337 us; speedup vs baseline: 1.1865x; 1.0834x over previous
//
#include <hip/hip_runtime.h>

#define NN 50000
#define NE 600000

typedef unsigned short ushort_t;
typedef ushort_t ushortx8 __attribute__((ext_vector_type(8)));
typedef ushort_t ushortx4 __attribute__((ext_vector_type(4)));
typedef short bf16x8 __attribute__((ext_vector_type(8)));
typedef float f32x4 __attribute__((ext_vector_type(4)));
typedef int intx2 __attribute__((ext_vector_type(2)));
typedef float fltx4 __attribute__((ext_vector_type(4)));

__device__ __forceinline__ float bf2f(ushort_t u) {
    union { unsigned int i; float f; } c;
    c.i = ((unsigned int)u) << 16;
    return c.f;
}
__device__ __forceinline__ ushort_t f2bf(float f) {
    union { float f; unsigned int i; } c;
    c.f = f;
    unsigned int u = c.i;
    unsigned int r = u + 0x7FFFu + ((u >> 16) & 1u);   // RNE
    return (ushort_t)(r >> 16);
}
__device__ __forceinline__ unsigned cvtpk(float lo, float hi) {
    unsigned r;
    asm("v_cvt_pk_bf16_f32 %0, %1, %2" : "=v"(r) : "v"(lo), "v"(hi));
    return r;
}

// ---------------- x -> bf16 ----------------
__global__ void k_xbf(const float* __restrict__ X, ushort_t* __restrict__ XB) {
    size_t i = (size_t)blockIdx.x * 256 + threadIdx.x;   // one 8-elem chunk
    const float4* X4 = (const float4*)X;
    float4 a = X4[i * 2], b = X4[i * 2 + 1];
    union { unsigned u[4]; ushortx8 v; } cv;
    cv.u[0] = cvtpk(a.x, a.y);
    cv.u[1] = cvtpk(a.z, a.w);
    cv.u[2] = cvtpk(b.x, b.y);
    cv.u[3] = cvtpk(b.z, b.w);
    __builtin_nontemporal_store(cv.v, (ushortx8*)XB + i);
}

// ---------------- graph build ----------------

__global__ void k_count(const int* __restrict__ ei, int* __restrict__ cnt) {
    int e = blockIdx.x * 256 + threadIdx.x;
    if (e < NE) {
        int d = __builtin_nontemporal_load(ei + NE + e);
        atomicAdd(&cnt[d], 1);
    }
}

// scan of cnt -> rowptr (exclusive, per-block) + block sums; also dinv
__global__ void k_scan1(const int* __restrict__ cnt, int* __restrict__ rowptr,
                        int* __restrict__ bsum, float* __restrict__ dinv) {
    __shared__ int s[256];
    int t = threadIdx.x;
    int i = blockIdx.x * 256 + t;
    int v = (i < NN) ? cnt[i] : 0;
    if (i < NN) dinv[i] = rsqrtf(1.0f + (float)v);
    s[t] = v;
    __syncthreads();
    for (int d = 1; d < 256; d <<= 1) {
        int tmp = (t >= d) ? s[t - d] : 0;
        __syncthreads();
        s[t] += tmp;
        __syncthreads();
    }
    if (i < NN) rowptr[i] = s[t] - v;
    if (t == 255) bsum[blockIdx.x] = s[255];
}

// blocks 0..255: weight prep (transpose + bf16). block 256: scan of bsum -> boff.
__global__ void k_scan2_prep(int* __restrict__ bsum, int* __restrict__ boff, int nb,
                             const float* __restrict__ Wp1, const float* __restrict__ Wv1,
                             const float* __restrict__ Wp2, const float* __restrict__ Wv2,
                             ushort_t* __restrict__ Wt1, ushort_t* __restrict__ Wt2p,
                             ushort_t* __restrict__ Wt2v) {
    int b = blockIdx.x, t = threadIdx.x;
    if (b < 128) {
        int idx = b * 256 + t;
        int n = idx >> 7, k = idx & 127;
        float v = (n < 128) ? Wp1[k * 128 + n] : Wv1[k * 128 + (n - 128)];
        Wt1[n * 128 + k] = f2bf(v);
    } else if (b < 192) {
        int idx = (b - 128) * 256 + t;
        int n = idx >> 7, k = idx & 127;
        Wt2p[n * 128 + k] = f2bf(Wp2[k * 128 + n]);
    } else if (b < 256) {
        int idx = (b - 192) * 256 + t;
        int n = idx >> 7, k = idx & 127;
        Wt2v[n * 128 + k] = f2bf(Wv2[k * 128 + n]);
    } else {
        __shared__ int s[256];
        int v = (t < nb) ? bsum[t] : 0;
        s[t] = v;
        __syncthreads();
        for (int d = 1; d < 256; d <<= 1) {
            int tmp = (t >= d) ? s[t - d] : 0;
            __syncthreads();
            s[t] += tmp;
            __syncthreads();
        }
        boff[t] = s[t] - v;
    }
}

// rc[i] = {final_start, cnt}
__global__ void k_scan3rc(const int* __restrict__ rowptr, const int* __restrict__ cnt,
                          const int* __restrict__ boff, int2* __restrict__ rc) {
    int i = blockIdx.x * 256 + threadIdx.x;
    if (i < NN) {
        int2 v;
        v.x = rowptr[i] + boff[blockIdx.x];
        v.y = cnt[i];
        rc[i] = v;
    }
}

__global__ void k_fill(const int* __restrict__ ei, const int2* __restrict__ rc,
                       int* __restrict__ fill, const float* __restrict__ dinv,
                       int2* __restrict__ edges) {
    int e = blockIdx.x * 256 + threadIdx.x;
    if (e < NE) {
        int s = __builtin_nontemporal_load(ei + e);
        int d = __builtin_nontemporal_load(ei + NE + e);
        int pos = rc[d].x + atomicAdd(&fill[d], 1);
        int2 pr;
        pr.x = s;
        pr.y = __float_as_int(dinv[s] * dinv[d]);
        edges[pos] = pr;
    }
}

// ---------------- aggregation, 128 features bf16 (layer-1 input x) --------------
// wave per node; 4 teams of 16 lanes (16B each = 256B row). Predicated 4-slot
// burst; dead slots gather row i (L1-hot) with weight 0.
__global__ __launch_bounds__(256) void k_agg128(const ushort_t* __restrict__ H,
                                                ushort_t* __restrict__ OUT,
                                                const float* __restrict__ dinv,
                                                const int2* __restrict__ rc,
                                                const int2* __restrict__ edges) {
    int wv = threadIdx.x >> 6;
    int l = threadIdx.x & 63;
    int i = blockIdx.x * 4 + wv;
    if (i >= NN) return;
    int t2 = l >> 4, q = l & 15;
    const ushortx8* H8 = (const ushortx8*)H;

    float a0[8] = {}, a1[8] = {};
    float di = dinv[i];
    float ws = (t2 == 0) ? di * di : 0.f;
    ushortx8 hv = H8[(size_t)i * 16 + q];
#pragma unroll
    for (int k = 0; k < 8; ++k) a0[k] = ws * bf2f(hv[k]);

    int2 rcv = rc[i];
    int st = rcv.x, n = rcv.y;

    for (int j = t2; j < n; j += 16) {
        int idx[4];
        float w[4];
#pragma unroll
        for (int s = 0; s < 4; ++s) {
            int jj = j + 4 * s;            // this team's edge index within row
            bool valid = jj < n;
            intx2 em = __builtin_nontemporal_load(
                (const intx2*)edges + (valid ? st + jj : st));
            idx[s] = valid ? em.x : i;
            w[s] = valid ? __int_as_float(em.y) : 0.f;
        }
        ushortx8 hh[4];
#pragma unroll
        for (int s = 0; s < 4; ++s) hh[s] = H8[(size_t)idx[s] * 16 + q];
#pragma unroll
        for (int k = 0; k < 8; ++k) a0[k] += w[0] * bf2f(hh[0][k]);
#pragma unroll
        for (int k = 0; k < 8; ++k) a1[k] += w[1] * bf2f(hh[1][k]);
#pragma unroll
        for (int k = 0; k < 8; ++k) a0[k] += w[2] * bf2f(hh[2][k]);
#pragma unroll
        for (int k = 0; k < 8; ++k) a1[k] += w[3] * bf2f(hh[3][k]);
    }
#pragma unroll
    for (int k = 0; k < 8; ++k) a0[k] += a1[k];
#pragma unroll
    for (int k = 0; k < 8; ++k) {
        a0[k] += __shfl_xor(a0[k], 16, 64);
        a0[k] += __shfl_xor(a0[k], 32, 64);
    }
    if (l < 16) {
        ushortx8 o = {f2bf(a0[0]), f2bf(a0[1]), f2bf(a0[2]), f2bf(a0[3]),
                      f2bf(a0[4]), f2bf(a0[5]), f2bf(a0[6]), f2bf(a0[7])};
        __builtin_nontemporal_store(o, (ushortx8*)OUT + (size_t)i * 16 + q);
    }
}

// ---------------- aggregation, 256 features bf16, plain (no bias/relu) ----------
__global__ __launch_bounds__(256) void k_agg256(const ushort_t* __restrict__ H,
                                                ushort_t* __restrict__ OUT,
                                                const float* __restrict__ dinv,
                                                const int2* __restrict__ rc,
                                                const int2* __restrict__ edges) {
    int wv = threadIdx.x >> 6;
    int l = threadIdx.x & 63;
    int i = blockIdx.x * 4 + wv;
    if (i >= NN) return;
    int h = l >> 5, q = l & 31;
    const ushortx8* H8 = (const ushortx8*)H;

    float a0[8] = {}, a1[8] = {};
    float di = dinv[i];
    float ws = (h == 0) ? di * di : 0.f;
    ushortx8 hv = H8[(size_t)i * 32 + q];
#pragma unroll
    for (int k = 0; k < 8; ++k) a0[k] = ws * bf2f(hv[k]);

    int2 rcv = rc[i];
    int st = rcv.x, n = rcv.y;

    for (int j = h; j < n; j += 8) {
        int idx[4];
        float w[4];
#pragma unroll
        for (int s = 0; s < 4; ++s) {
            int jj = j + 2 * s;
            bool valid = jj < n;
            intx2 em = __builtin_nontemporal_load(
                (const intx2*)edges + (valid ? st + jj : st));
            idx[s] = valid ? em.x : i;
            w[s] = valid ? __int_as_float(em.y) : 0.f;
        }
        ushortx8 hh[4];
#pragma unroll
        for (int s = 0; s < 4; ++s) hh[s] = H8[(size_t)idx[s] * 32 + q];
#pragma unroll
        for (int k = 0; k < 8; ++k) a0[k] += w[0] * bf2f(hh[0][k]);
#pragma unroll
        for (int k = 0; k < 8; ++k) a1[k] += w[1] * bf2f(hh[1][k]);
#pragma unroll
        for (int k = 0; k < 8; ++k) a0[k] += w[2] * bf2f(hh[2][k]);
#pragma unroll
        for (int k = 0; k < 8; ++k) a1[k] += w[3] * bf2f(hh[3][k]);
    }
#pragma unroll
    for (int k = 0; k < 8; ++k) a0[k] += a1[k];
#pragma unroll
    for (int k = 0; k < 8; ++k) a0[k] += __shfl_xor(a0[k], 32, 64);

    if (h == 0) {
        ushortx8 o = {f2bf(a0[0]), f2bf(a0[1]), f2bf(a0[2]), f2bf(a0[3]),
                      f2bf(a0[4]), f2bf(a0[5]), f2bf(a0[6]), f2bf(a0[7])};
        __builtin_nontemporal_store(o, (ushortx8*)OUT + (size_t)i * 32 + q);
    }
}

// ---------------- layer-1 MFMA GEMM: f1 = relu(ag0[N,128] @ [Wp1|Wv1] + b) -------
__global__ __launch_bounds__(256) void k_gemm1(const ushort_t* __restrict__ A,
                                               const ushort_t* __restrict__ Wt1,
                                               const float* __restrict__ bL,
                                               const float* __restrict__ bH,
                                               ushort_t* __restrict__ C, int nrows) {
    __shared__ ushort_t Wl[256 * 128];
    int t = threadIdx.x;
    const ushortx8* Wg = (const ushortx8*)Wt1;
#pragma unroll
    for (int i = 0; i < 16; ++i) {
        int c = i * 256 + t;
        int row = c >> 4, slot = c & 15;
        int db = row * 256 + ((slot * 16) ^ ((row & 7) << 4));
        *(ushortx8*)((char*)Wl + db) = Wg[c];
    }
    __syncthreads();

    int w = t >> 6, l = t & 63, m = l & 15, g = l >> 4;
    int r0 = blockIdx.x * 64 + w * 16;
    if (r0 >= nrows) return;

    const ushort_t* Arow = A + (size_t)(r0 + m) * 128;
    bf16x8 af[4];
#pragma unroll
    for (int kk = 0; kk < 4; ++kk) af[kk] = *(const bf16x8*)(Arow + kk * 32 + g * 8);

    f32x4 acc[16];
#pragma unroll
    for (int nt = 0; nt < 16; ++nt) acc[nt] = (f32x4){0.f, 0.f, 0.f, 0.f};
    int sw = (m & 7) << 4;
#pragma unroll
    for (int nt = 0; nt < 16; ++nt) {
        const char* Wb = (const char*)Wl + (nt * 16 + m) * 256;
#pragma unroll
        for (int kk = 0; kk < 4; ++kk) {
            bf16x8 wf = *(const bf16x8*)(Wb + ((kk * 64 + g * 16) ^ sw));
            acc[nt] = __builtin_amdgcn_mfma_f32_16x16x32_bf16(wf, af[kk], acc[nt], 0, 0, 0);
        }
    }
#pragma unroll
    for (int nt = 0; nt < 16; ++nt) {
        const float* bb = (nt < 8) ? (bL + nt * 16 + g * 4) : (bH + (nt - 8) * 16 + g * 4);
        float4 bv = *(const float4*)bb;
        ushortx4 o = {f2bf(fmaxf(acc[nt][0] + bv.x, 0.f)),
                      f2bf(fmaxf(acc[nt][1] + bv.y, 0.f)),
                      f2bf(fmaxf(acc[nt][2] + bv.z, 0.f)),
                      f2bf(fmaxf(acc[nt][3] + bv.w, 0.f))};
        *(ushortx4*)(C + (size_t)(r0 + m) * 256 + nt * 16 + g * 4) = o;
    }
}

// ---------------- layer-2 dual MFMA GEMM: f2 = relu(ag1 @ blockdiag(W2) + b) -----
__global__ __launch_bounds__(256) void k_gemm2(const ushort_t* __restrict__ A,
                                               const ushort_t* __restrict__ Wp,
                                               const ushort_t* __restrict__ Wv,
                                               const float* __restrict__ bL,
                                               const float* __restrict__ bH,
                                               ushort_t* __restrict__ C, int nrows) {
    __shared__ ushort_t Wl[2 * 128 * 128];
    int t = threadIdx.x;
    const ushortx8* Wgp = (const ushortx8*)Wp;
    const ushortx8* Wgv = (const ushortx8*)Wv;
#pragma unroll
    for (int i = 0; i < 8; ++i) {
        int c = i * 256 + t;
        int row = c >> 4, slot = c & 15;
        int db = row * 256 + ((slot * 16) ^ ((row & 7) << 4));
        *(ushortx8*)((char*)Wl + db) = Wgp[c];
        *(ushortx8*)((char*)Wl + 32768 + db) = Wgv[c];
    }
    __syncthreads();

    int w = t >> 6, l = t & 63, m = l & 15, g = l >> 4;
    int r0 = blockIdx.x * 64 + w * 16;
    if (r0 >= nrows) return;

    const ushort_t* Arow = A + (size_t)(r0 + m) * 256;
    bf16x8 alo[4], ahi[4];
#pragma unroll
    for (int kk = 0; kk < 4; ++kk) {
        alo[kk] = *(const bf16x8*)(Arow + kk * 32 + g * 8);
        ahi[kk] = *(const bf16x8*)(Arow + 128 + kk * 32 + g * 8);
    }

    f32x4 accp[8], accv[8];
#pragma unroll
    for (int nt = 0; nt < 8; ++nt) {
        accp[nt] = (f32x4){0.f, 0.f, 0.f, 0.f};
        accv[nt] = (f32x4){0.f, 0.f, 0.f, 0.f};
    }
    int sw = (m & 7) << 4;
#pragma unroll
    for (int nt = 0; nt < 8; ++nt) {
        const char* Wbp = (const char*)Wl + (nt * 16 + m) * 256;
        const char* Wbv = Wbp + 32768;
#pragma unroll
        for (int kk = 0; kk < 4; ++kk) {
            int off = (kk * 64 + g * 16) ^ sw;
            bf16x8 wfp = *(const bf16x8*)(Wbp + off);
            accp[nt] = __builtin_amdgcn_mfma_f32_16x16x32_bf16(wfp, alo[kk], accp[nt], 0, 0, 0);
            bf16x8 wfv = *(const bf16x8*)(Wbv + off);
            accv[nt] = __builtin_amdgcn_mfma_f32_16x16x32_bf16(wfv, ahi[kk], accv[nt], 0, 0, 0);
        }
    }
#pragma unroll
    for (int nt = 0; nt < 8; ++nt) {
        float4 bp = *(const float4*)(bL + nt * 16 + g * 4);
        float4 bv = *(const float4*)(bH + nt * 16 + g * 4);
        ushortx4 op = {f2bf(fmaxf(accp[nt][0] + bp.x, 0.f)),
                       f2bf(fmaxf(accp[nt][1] + bp.y, 0.f)),
                       f2bf(fmaxf(accp[nt][2] + bp.z, 0.f)),
                       f2bf(fmaxf(accp[nt][3] + bp.w, 0.f))};
        ushortx4 ov = {f2bf(fmaxf(accv[nt][0] + bv.x, 0.f)),
                       f2bf(fmaxf(accv[nt][1] + bv.y, 0.f)),
                       f2bf(fmaxf(accv[nt][2] + bv.z, 0.f)),
                       f2bf(fmaxf(accv[nt][3] + bv.w, 0.f))};
        *(ushortx4*)(C + (size_t)(r0 + m) * 256 + nt * 16 + g * 4) = op;
        *(ushortx4*)(C + (size_t)(r0 + m) * 256 + 128 + nt * 16 + g * 4) = ov;
    }
}

// ---------------- small GEMM (bf16 in): fs[:,0:8]=f2[:,0:128]@Wp3 ; fs[:,8]=f2[:,128:256]@Wv3
__global__ __launch_bounds__(256) void k_small(const ushort_t* __restrict__ F2,
                                               const float* __restrict__ Wp3,
                                               const float* __restrict__ Wv3,
                                               float* __restrict__ FS) {
    __shared__ float Wp[8 * 128];
    __shared__ float Wv[128];
    int t = threadIdx.x;
    for (int j = t; j < 1024; j += 256) {
        int k = j >> 3, c = j & 7;
        Wp[c * 128 + k] = Wp3[j];
    }
    if (t < 128) Wv[t] = Wv3[t];
    __syncthreads();
    int row = blockIdx.x * 256 + t;
    if (row >= NN) return;
    const ushortx8* F8 = (const ushortx8*)F2;
    size_t base = (size_t)row * 32;
    float acc[9] = {};
#pragma unroll 2
    for (int kc = 0; kc < 16; ++kc) {
        ushortx8 p = F8[base + kc];
        ushortx8 v = F8[base + 16 + kc];
#pragma unroll
        for (int jj = 0; jj < 8; ++jj) {
            float pv = bf2f(p[jj]);
            int k = kc * 8 + jj;
#pragma unroll
            for (int c = 0; c < 8; ++c) acc[c] += pv * Wp[c * 128 + k];
            acc[8] += bf2f(v[jj]) * Wv[k];
        }
    }
    float4* FSo = (float4*)(FS + (size_t)row * 12);
    float4 o0 = {acc[0], acc[1], acc[2], acc[3]};
    float4 o1 = {acc[4], acc[5], acc[6], acc[7]};
    float4 o2 = {acc[8], 0.f, 0.f, 0.f};
    FSo[0] = o0; FSo[1] = o1; FSo[2] = o2;
}

// ---------------- final fused aggregation (8 logits + 1 value) ----------------
__global__ void k_agg9(const float* __restrict__ FS, float* __restrict__ out_logits,
                       float* __restrict__ out_v, const float* __restrict__ bp3,
                       const float* __restrict__ bv3, const float* __restrict__ dinv,
                       const int2* __restrict__ rc, const int2* __restrict__ edges) {
    int i = blockIdx.x * 256 + threadIdx.x;
    if (i >= NN) return;
    float di = dinv[i];
    float w0 = di * di;
    const float4* F = (const float4*)FS;
    size_t b0 = (size_t)i * 3;
    float4 x0 = F[b0], x1 = F[b0 + 1], x2 = F[b0 + 2];
    float a[9];
    a[0] = w0 * x0.x; a[1] = w0 * x0.y; a[2] = w0 * x0.z; a[3] = w0 * x0.w;
    a[4] = w0 * x1.x; a[5] = w0 * x1.y; a[6] = w0 * x1.z; a[7] = w0 * x1.w;
    a[8] = w0 * x2.x;
    int2 rcv = rc[i];
    int st = rcv.x, n = rcv.y;
    for (int j = 0; j < n; ++j) {
        int2 e = edges[st + j];
        float w = __int_as_float(e.y);
        size_t sb = (size_t)e.x * 3;
        float4 y0 = F[sb], y1 = F[sb + 1], y2 = F[sb + 2];
        a[0] += w * y0.x; a[1] += w * y0.y; a[2] += w * y0.z; a[3] += w * y0.w;
        a[4] += w * y1.x; a[5] += w * y1.y; a[6] += w * y1.z; a[7] += w * y1.w;
        a[8] += w * y2.x;
    }
    float4 bpa = *(const float4*)bp3;
    float4 bpb = *(const float4*)(bp3 + 4);
    fltx4 o0 = {a[0] + bpa.x, a[1] + bpa.y, a[2] + bpa.z, a[3] + bpa.w};
    fltx4 o1 = {a[4] + bpb.x, a[5] + bpb.y, a[6] + bpb.z, a[7] + bpb.w};
    __builtin_nontemporal_store(o0, (fltx4*)out_logits + (size_t)i * 2);
    __builtin_nontemporal_store(o1, (fltx4*)out_logits + (size_t)i * 2 + 1);
    __builtin_nontemporal_store(a[8] + bv3[0], out_v + i);
}

// ---------------- launcher ----------------
extern "C" void kernel_launch(void* const* d_in, const int* in_sizes, int n_in,
                              void* d_out, int out_size, void* d_ws, size_t ws_size,
                              hipStream_t stream) {
    const float* x   = (const float*)d_in[0];
    const int*   ei  = (const int*)d_in[1];
    const float* Wp1 = (const float*)d_in[2],  *bp1 = (const float*)d_in[3];
    const float* Wp2 = (const float*)d_in[4],  *bp2 = (const float*)d_in[5];
    const float* Wp3 = (const float*)d_in[6],  *bp3 = (const float*)d_in[7];
    const float* Wv1 = (const float*)d_in[8],  *bv1 = (const float*)d_in[9];
    const float* Wv2 = (const float*)d_in[10], *bv2 = (const float*)d_in[11];
    const float* Wv3 = (const float*)d_in[12], *bv3 = (const float*)d_in[13];
    float* out_logits = (float*)d_out;
    float* out_v = (float*)d_out + (size_t)NN * 8;

    char* w = (char*)d_ws;
    auto alloc = [&](size_t bytes) {
        char* p = w;
        w += (bytes + 255) & ~(size_t)255;
        return p;
    };
    int*      cntfill = (int*)alloc((size_t)2 * NN * 4);
    int*      cnt    = cntfill;
    int*      fill   = cntfill + NN;
    int*      rowptr = (int*)alloc(NN * 4);
    int*      bsum   = (int*)alloc(256 * 4);
    int*      boff   = (int*)alloc(256 * 4);
    float*    dinv   = (float*)alloc(NN * 4);
    int2*     rc     = (int2*)alloc((size_t)NN * 8);
    int2*     edges  = (int2*)alloc((size_t)NE * 8);
    ushort_t* Wt1    = (ushort_t*)alloc(256 * 128 * 2);
    ushort_t* Wt2p   = (ushort_t*)alloc(128 * 128 * 2);
    ushort_t* Wt2v   = (ushort_t*)alloc(128 * 128 * 2);
    ushort_t* xb     = (ushort_t*)alloc((size_t)NN * 128 * 2);
    ushort_t* ag0    = (ushort_t*)alloc((size_t)NN * 128 * 2);
    ushort_t* f1b    = (ushort_t*)alloc((size_t)NN * 256 * 2);
    ushort_t* ag1    = (ushort_t*)alloc((size_t)NN * 256 * 2);
    ushort_t* f2b    = (ushort_t*)alloc((size_t)NN * 256 * 2);
    float*    fs     = (float*)alloc((size_t)NN * 12 * 4);

    const int NB = (NN + 255) / 256;   // 196
    const int EB = (NE + 255) / 256;
    const int GB = (NN + 63) / 64;     // 782
    const int AB = NN / 4;             // 12500

    k_xbf<<<3125, 256, 0, stream>>>(x, xb);
    (void)hipMemsetAsync(cntfill, 0, (size_t)2 * NN * 4, stream);
    k_count<<<EB, 256, 0, stream>>>(ei, cnt);
    k_scan1<<<NB, 256, 0, stream>>>(cnt, rowptr, bsum, dinv);
    k_scan2_prep<<<257, 256, 0, stream>>>(bsum, boff, NB, Wp1, Wv1, Wp2, Wv2,
                                          Wt1, Wt2p, Wt2v);
    k_scan3rc<<<NB, 256, 0, stream>>>(rowptr, cnt, boff, rc);
    k_fill<<<EB, 256, 0, stream>>>(ei, rc, fill, dinv, edges);

    // layer 1: agg(x) then GEMM (+bias+relu)   [agg(x@W) == agg(x)@W]
    k_agg128<<<AB, 256, 0, stream>>>(xb, ag0, dinv, rc, edges);
    k_gemm1<<<GB, 256, 0, stream>>>(ag0, Wt1, bp1, bv1, f1b, NN);
    // layer 2: agg(f1) then block-diagonal GEMM (+bias+relu)
    k_agg256<<<AB, 256, 0, stream>>>(f1b, ag1, dinv, rc, edges);
    k_gemm2<<<GB, 256, 0, stream>>>(ag1, Wt2p, Wt2v, bp2, bv2, f2b, NN);
    // layer 3: GEMM to 9 cols, then gather
    k_small<<<NB, 256, 0, stream>>>(f2b, Wp3, Wv3, fs);
    k_agg9<<<NB, 256, 0, stream>>>(fs, out_logits, out_v, bp3, bv3, dinv, rc, edges);
}